// Round 3
// baseline (71.925 us; speedup 1.0000x reference)
//
#include <hip/hip_runtime.h>
#include <hip/hip_cooperative_groups.h>

#define BATCH 8192
#define DIM 128
#define NCLS 6
#define NPAIRS 15
#define NBLK 64
#define NTHR 512
#define WPB (NTHR / 64)           // 8 waves per block
#define NWAVES (NBLK * WPB)       // 512 waves
#define NPAIRROWS (BATCH / 2)     // 4096 row-pairs; 4096/512 = 8 iters exactly
#define ZLEN (NCLS * DIM)         // 768

// d_ws layout: float gpart[NBLK][ZLEN]; float gcntp[NBLK][NCLS]
// ≈ 198 KB. Fully rewritten every call (poison-safe).

__global__ __launch_bounds__(NTHR) void fused_kernel(
    const float* __restrict__ latent,
    const int* __restrict__ label,
    float* __restrict__ gpart,
    float* __restrict__ gcntp,
    float* __restrict__ out)
{
    __shared__ float lz[WPB][ZLEN];
    __shared__ int   lcnt[WPB][NCLS];

    const int tid  = threadIdx.x;
    const int lane = tid & 63;
    const int w    = tid >> 6;
    const int half = lane >> 5;        // which row of the pair
    const int hl   = lane & 31;        // lane within 32-lane half
    const int gw   = blockIdx.x * WPB + w;

    float4 acc[NCLS];
    int    cnt[NCLS];
    #pragma unroll
    for (int c = 0; c < NCLS; ++c) { acc[c] = make_float4(0.f, 0.f, 0.f, 0.f); cnt[c] = 0; }

    #pragma unroll 2
    for (int pair = gw; pair < NPAIRROWS; pair += NWAVES) {
        const int row = pair * 2 + half;
        const float4 v = *reinterpret_cast<const float4*>(
            latent + (size_t)row * DIM + hl * 4);
        float ss = v.x * v.x + v.y * v.y + v.z * v.z + v.w * v.w;
        #pragma unroll
        for (int off = 16; off >= 1; off >>= 1)
            ss += __shfl_xor(ss, off);
        const float rn = 1.0f / sqrtf(ss);   // correctly-rounded (no rsqrt bias)
        const int lab = label[row];
        #pragma unroll
        for (int c = 0; c < NCLS; ++c) {
            const float m = (lab == c) ? rn : 0.0f;   // predicated, static index
            acc[c].x += v.x * m;  acc[c].y += v.y * m;
            acc[c].z += v.z * m;  acc[c].w += v.w * m;
            cnt[c]   += (hl == 0) ? (int)(lab == c) : 0;
        }
    }

    // fold the two 32-lane halves together
    #pragma unroll
    for (int c = 0; c < NCLS; ++c) {
        acc[c].x += __shfl_xor(acc[c].x, 32);
        acc[c].y += __shfl_xor(acc[c].y, 32);
        acc[c].z += __shfl_xor(acc[c].z, 32);
        acc[c].w += __shfl_xor(acc[c].w, 32);
        cnt[c]   += __shfl_xor(cnt[c], 32);
    }

    if (lane < 32) {
        #pragma unroll
        for (int c = 0; c < NCLS; ++c)
            *reinterpret_cast<float4*>(&lz[w][c * DIM + lane * 4]) = acc[c];
    }
    if (lane == 0) {
        #pragma unroll
        for (int c = 0; c < NCLS; ++c) lcnt[w][c] = cnt[c];
    }
    __syncthreads();

    // block-level reduce across the 8 waves → per-block partials in ws
    for (int e = tid; e < ZLEN; e += NTHR) {
        float s = 0.f;
        #pragma unroll
        for (int ww = 0; ww < WPB; ++ww) s += lz[ww][e];
        gpart[blockIdx.x * ZLEN + e] = s;
    }
    if (tid < NCLS) {
        int s = 0;
        #pragma unroll
        for (int ww = 0; ww < WPB; ++ww) s += lcnt[ww][tid];
        gcntp[blockIdx.x * NCLS + tid] = (float)s;
    }

    cooperative_groups::this_grid().sync();

    // ---- Phase B: block 0 reduces partials + epilogue ----
    if (blockIdx.x != 0) return;

    __shared__ float zz[ZLEN];
    __shared__ float cf[NCLS];
    __shared__ float ps[NPAIRS];

    for (int e = tid; e < ZLEN; e += NTHR) {
        float s = 0.f;
        #pragma unroll 8
        for (int b = 0; b < NBLK; ++b) s += gpart[b * ZLEN + e];
        zz[e] = s;
    }
    if (tid < NCLS) {
        float s = 0.f;
        #pragma unroll 8
        for (int b = 0; b < NBLK; ++b) s += gcntp[b * NCLS + tid];
        cf[tid] = s;
    }
    if (tid >= NTHR - NPAIRS) ps[tid - (NTHR - NPAIRS)] = 0.f;
    __syncthreads();

    if (tid < DIM) {
        float zi[NCLS];
        #pragma unroll
        for (int c = 0; c < NCLS; ++c) zi[c] = zz[c * DIM + tid];
        int p = 0;
        #pragma unroll
        for (int i = 0; i < NCLS; ++i) {
            #pragma unroll
            for (int j = i + 1; j < NCLS; ++j, ++p)
                atomicAdd(&ps[p], zi[i] * zi[j]);
        }
    }
    __syncthreads();

    if (tid == 0) {
        float acc2 = 0.f;
        int p = 0;
        for (int i = 0; i < NCLS; ++i) {
            const float n = cf[i];
            const float denom = fmaxf(n * n - n, 1.0f);
            for (int j = i + 1; j < NCLS; ++j, ++p)
                acc2 += ps[p] / denom;
        }
        out[0] = acc2 / (float)NPAIRS;
    }
}

extern "C" void kernel_launch(void* const* d_in, const int* in_sizes, int n_in,
                              void* d_out, int out_size, void* d_ws, size_t ws_size,
                              hipStream_t stream) {
    const float* latent = (const float*)d_in[0];
    const int* label = (const int*)d_in[1];
    float* out = (float*)d_out;

    float* gpart = (float*)d_ws;                 // [NBLK][ZLEN]
    float* gcntp = gpart + NBLK * ZLEN;          // [NBLK][NCLS]

    void* args[] = { (void*)&latent, (void*)&label, (void*)&gpart,
                     (void*)&gcntp, (void*)&out };
    hipLaunchCooperativeKernel((void*)fused_kernel, dim3(NBLK), dim3(NTHR),
                               args, 0, stream);
}

// Round 4
// 44.046 us; speedup vs baseline: 1.6330x; 1.6330x over previous
//
#include <hip/hip_runtime.h>

#define BATCH 8192
#define DIM 128
#define NCLS 6
#define NPAIRS 15
#define NBLK 128
#define NTHR 512
#define WPB (NTHR / 64)           // 8 waves per block
#define NWAVES (NBLK * WPB)       // 1024 waves
#define RPW (BATCH / NWAVES)      // 8 rows per wave (contiguous)
#define ITERS (RPW / 2)           // 4 pair-iters, fully unrolled
#define ZLEN (NCLS * DIM)         // 768
#define NTHR2 832                 // 13 waves; >= ZLEN + NCLS = 774

// d_ws layout: float gpart[NBLK][ZLEN]; float gcntp[NBLK][NCLS]
// ≈ 396 KB, fully rewritten every call (poison-safe).

__global__ __launch_bounds__(NTHR) void class_sum_kernel(
    const float* __restrict__ latent,
    const int* __restrict__ label,
    float* __restrict__ gpart,
    float* __restrict__ gcntp)
{
    __shared__ float lz[WPB][ZLEN];
    __shared__ int   lcnt[WPB][NCLS];

    const int tid  = threadIdx.x;
    const int lane = tid & 63;
    const int w    = tid >> 6;
    const int half = lane >> 5;        // which row of each pair
    const int hl   = lane & 31;        // lane within 32-lane half
    const int gw   = blockIdx.x * WPB + w;
    const int row0 = gw * RPW + half;  // this half handles rows row0 + 2j

    // Issue ALL loads up front: 4 independent float4 vmem + 4 label loads
    const float* bp = latent + (size_t)row0 * DIM + hl * 4;
    float4 v[ITERS];
    int labs[ITERS];
    #pragma unroll
    for (int j = 0; j < ITERS; ++j)
        v[j] = *reinterpret_cast<const float4*>(bp + (size_t)j * 2 * DIM);
    #pragma unroll
    for (int j = 0; j < ITERS; ++j)
        labs[j] = label[row0 + 2 * j];

    float4 acc[NCLS];
    int    cnt[NCLS];
    #pragma unroll
    for (int c = 0; c < NCLS; ++c) { acc[c] = make_float4(0.f, 0.f, 0.f, 0.f); cnt[c] = 0; }

    #pragma unroll
    for (int j = 0; j < ITERS; ++j) {
        float ss = v[j].x * v[j].x + v[j].y * v[j].y
                 + v[j].z * v[j].z + v[j].w * v[j].w;
        #pragma unroll
        for (int off = 16; off >= 1; off >>= 1)
            ss += __shfl_xor(ss, off);                 // reduce within 32-lane half
        const float rn = 1.0f / sqrtf(ss);             // correctly-rounded (no rsqrt bias)
        const int lab = labs[j];
        #pragma unroll
        for (int c = 0; c < NCLS; ++c) {
            const float m = (lab == c) ? rn : 0.0f;    // predicated, static index
            acc[c].x += v[j].x * m;  acc[c].y += v[j].y * m;
            acc[c].z += v[j].z * m;  acc[c].w += v[j].w * m;
            cnt[c]   += (hl == 0) ? (int)(lab == c) : 0;
        }
    }

    // fold the two 32-lane halves together
    #pragma unroll
    for (int c = 0; c < NCLS; ++c) {
        acc[c].x += __shfl_xor(acc[c].x, 32);
        acc[c].y += __shfl_xor(acc[c].y, 32);
        acc[c].z += __shfl_xor(acc[c].z, 32);
        acc[c].w += __shfl_xor(acc[c].w, 32);
        cnt[c]   += __shfl_xor(cnt[c], 32);
    }

    if (lane < 32) {
        #pragma unroll
        for (int c = 0; c < NCLS; ++c)
            *reinterpret_cast<float4*>(&lz[w][c * DIM + lane * 4]) = acc[c];
    }
    if (lane == 0) {
        #pragma unroll
        for (int c = 0; c < NCLS; ++c) lcnt[w][c] = cnt[c];
    }
    __syncthreads();

    // block-level reduce across the 8 waves → per-block partials in ws
    for (int e = tid; e < ZLEN; e += NTHR) {
        float s = 0.f;
        #pragma unroll
        for (int ww = 0; ww < WPB; ++ww) s += lz[ww][e];
        gpart[blockIdx.x * ZLEN + e] = s;
    }
    if (tid < NCLS) {
        int s = 0;
        #pragma unroll
        for (int ww = 0; ww < WPB; ++ww) s += lcnt[ww][tid];
        gcntp[blockIdx.x * NCLS + tid] = (float)s;
    }
}

__global__ __launch_bounds__(NTHR2) void finalize_kernel(
    const float* __restrict__ gpart,
    const float* __restrict__ gcntp,
    float* __restrict__ out)
{
    __shared__ float zz[ZLEN];
    __shared__ float cf[NCLS];
    __shared__ float ps[NPAIRS];
    const int tid = threadIdx.x;

    if (tid < ZLEN) {
        float s = 0.f;
        #pragma unroll 16
        for (int b = 0; b < NBLK; ++b) s += gpart[b * ZLEN + tid];
        zz[tid] = s;
    } else if (tid < ZLEN + NCLS) {
        const int c = tid - ZLEN;
        float s = 0.f;
        #pragma unroll 16
        for (int b = 0; b < NBLK; ++b) s += gcntp[b * NCLS + c];
        cf[c] = s;
    }
    if (tid >= NTHR2 - NPAIRS) ps[tid - (NTHR2 - NPAIRS)] = 0.f;
    __syncthreads();

    if (tid < DIM) {
        float zi[NCLS];
        #pragma unroll
        for (int c = 0; c < NCLS; ++c) zi[c] = zz[c * DIM + tid];
        int p = 0;
        #pragma unroll
        for (int i = 0; i < NCLS; ++i) {
            #pragma unroll
            for (int j = i + 1; j < NCLS; ++j, ++p)
                atomicAdd(&ps[p], zi[i] * zi[j]);
        }
    }
    __syncthreads();

    if (tid == 0) {
        float acc2 = 0.f;
        int p = 0;
        for (int i = 0; i < NCLS; ++i) {
            const float n = cf[i];
            const float denom = fmaxf(n * n - n, 1.0f);
            for (int j = i + 1; j < NCLS; ++j, ++p)
                acc2 += ps[p] / denom;
        }
        out[0] = acc2 / (float)NPAIRS;
    }
}

extern "C" void kernel_launch(void* const* d_in, const int* in_sizes, int n_in,
                              void* d_out, int out_size, void* d_ws, size_t ws_size,
                              hipStream_t stream) {
    const float* latent = (const float*)d_in[0];
    const int* label = (const int*)d_in[1];
    float* out = (float*)d_out;

    float* gpart = (float*)d_ws;                 // [NBLK][ZLEN]
    float* gcntp = gpart + NBLK * ZLEN;          // [NBLK][NCLS]

    class_sum_kernel<<<NBLK, NTHR, 0, stream>>>(latent, label, gpart, gcntp);
    finalize_kernel<<<1, NTHR2, 0, stream>>>(gpart, gcntp, out);
}